// Round 13
// baseline (53.870 us; speedup 1.0000x reference)
//
#include <hip/hip_runtime.h>
#include <math.h>
#include <stdint.h>

// Problem: ProcessFeatures_83296595738632
// corr[bs,bg,i] = sum_{h,j,k} sat[bs,h,(i+j)%64,k] * grd[bg,h,j,15-k]
// orien = argmax_i corr (first-max); dot with cyclic shift orien, /||sat||
// distance[bg,bs] = 2-2*dot[bs,bg]; out: sat | grd | distance | orien(float)
//
// R13: K-split for occupancy. corr grid (6 nt6 x 96 bs x 2 khalf) = 1152
// blocks of 256 thr (4 waves; wave = j-slice of 8, 4 mtiles, R12-verified
// MT_STEP math). Partials (64x16 f32) to ws; separate 576-block epilogue
// does sum + argmax + norm + fp32 dot + distance.

#define BS   96
#define H    4
#define W    64
#define C    16
#define BG   96
#define HWC  (H*W*C)                  // 4096

#define SAT_ELEMS (BS*H*W*C)          // 393216
#define OUT_DIST  (2*SAT_ELEMS)       // 786432
#define OUT_ORIEN (OUT_DIST + BS*BG)  // 795648

#define WS_PART_OFF ((size_t)2 * SAT_ELEMS * 2)          // 1.5 MB (Bpk bytes)
#define WS_NEEDED   (WS_PART_OFF + (size_t)1152 * 1024 * 4)  // 6 MB

typedef __attribute__((ext_vector_type(4)))  short short4v;
typedef __attribute__((ext_vector_type(8)))  short short8v;
typedef __attribute__((ext_vector_type(4)))  float f32x4;

__device__ __forceinline__ void bsplit(float x, unsigned short& hi, unsigned short& lo) {
    unsigned int u = __float_as_uint(x);
    unsigned int r = (u + 0x7FFFu + ((u >> 16) & 1u)) >> 16;   // RNE to bf16
    hi = (unsigned short)r;
    float hf = __uint_as_float(r << 16);
    float l = x - hf;
    unsigned int ul = __float_as_uint(l);
    unsigned int rl = (ul + 0x7FFFu + ((ul >> 16) & 1u)) >> 16;
    lo = (unsigned short)rl;
}

// ---------------- prologue: pack B fragments (16x16x32 layout) + passthrough ----
// Fragment (j,kh,nt6,pl): lane l, elem e ->
//   B[k = (l>>4)*8+e][col = l&15] = grdR[j][nt6*16 + (l&15)][kh*32 + (l>>4)*8 + e]
//   grdR[j][bg][hk] = grd[bg][hk>>4][j][15-(hk&15)]
__global__ __launch_bounds__(512)
void pf_pack_b(const float* __restrict__ sat, const float* __restrict__ grd,
               unsigned short* __restrict__ Bpk, float* __restrict__ out)
{
    int t = blockIdx.x * 512 + threadIdx.x;    // < 49152 = 64j * 2kh * 6nt * 64lane
    int lane = t & 63;
    int f    = t >> 6;            // fragment id: ((j*2+kh)*6 + nt6)
    int nt6  = f % 6;
    int g    = f / 6;
    int kh   = g & 1;
    int j    = g >> 1;

    int col = nt6 * 16 + (lane & 15);
    int u   = lane >> 4;
    int h   = kh * 2 + (u >> 1);
    int k0  = (u & 1) * 8;        // hk = kh*32 + u*8 -> within-h offset k0

    const float* row = grd + ((size_t)(col * 4 + h) * 64 + j) * 16 + (8 - k0);
    float tmp[8];
    *(float4*)&tmp[0] = *(const float4*)(row);
    *(float4*)&tmp[4] = *(const float4*)(row + 4);

    short8v hv, lv;
    #pragma unroll
    for (int e = 0; e < 8; ++e) {
        unsigned short hi, lo;
        bsplit(tmp[7 - e], hi, lo);          // value[e] = grd[...][15-k0-e]
        hv[e] = (short)hi; lv[e] = (short)lo;
    }
    size_t base = (size_t)f << 10;           // 1024 ushorts per fragment pair
    *(short8v*)&Bpk[base + lane * 8]       = hv;   // plane 0 (hi)
    *(short8v*)&Bpk[base + 512 + lane * 8] = lv;   // plane 1 (lo)

    // passthrough copies: out[0..] = sat, out[SAT..] = grd
    const float4* s4 = (const float4*)sat;
    const float4* g4 = (const float4*)grd;
    float4* o4 = (float4*)out;
    #pragma unroll
    for (int idx = t; idx < 2 * SAT_ELEMS / 4; idx += 49152) {
        o4[idx] = (idx < SAT_ELEMS / 4) ? s4[idx] : g4[idx - SAT_ELEMS / 4];
    }
}

// ---------------- corr: MFMA bf16x4, K-split partials ----------------
#define MFMA16(a, b, c) __builtin_amdgcn_mfma_f32_16x16x32_bf16((a), (b), (c), 0, 0, 0)

__global__ __launch_bounds__(256, 4)
void pf_corr(const float* __restrict__ sat, const unsigned short* __restrict__ Bpk,
             float* __restrict__ part)
{
    __shared__ unsigned short sHi[4096], sLo[4096];   // satM planes, swizzled (16 KB)
    __shared__ float corrPart[4][64][17];             // 17.4 KB

    const int bs  = blockIdx.y;
    const int nt6 = blockIdx.x;          // 16-bg group
    const int kz  = blockIdx.z;          // K half (j in [kz*32, kz*32+32))
    const int tid = threadIdx.x;
    const int wv  = tid >> 6, lane = tid & 63;
    const int u   = lane >> 4, l15 = lane & 15;
    const int kq  = kz * 4 + wv;         // j-slice of 8: [kq*8, kq*8+8)

    // ---- stage satM (swizzled bf16 hi/lo) ----
    // satM[w][hk] = sat[bs][hk>>4][w][hk&15]; chunk cc=hk>>3 at slot cc^(w&7)
    {
        const float4* satB = (const float4*)(sat + (size_t)bs * HWC);
        #pragma unroll
        for (int t = tid; t < 1024; t += 256) {
            float4 v = satB[t];
            int e = 4 * t;
            int h = e >> 10, w = (e >> 4) & 63, k = e & 15;
            int cc = (h * 16 + k) >> 3;
            int dst = w * 64 + ((cc ^ (w & 7)) * 8) + (k & 7);
            short4v hvv, lvv;
            unsigned short hi, lo;
            bsplit(v.x, hi, lo); hvv[0] = hi; lvv[0] = lo;
            bsplit(v.y, hi, lo); hvv[1] = hi; lvv[1] = lo;
            bsplit(v.z, hi, lo); hvv[2] = hi; lvv[2] = lo;
            bsplit(v.w, hi, lo); hvv[3] = hi; lvv[3] = lo;
            *(short4v*)&sHi[dst] = hvv;
            *(short4v*)&sLo[dst] = lvv;
        }
    }
    __syncthreads();

    // ---- corr GEMM: bf16x4, 4 mtiles per wave, K-slice 8 j ----
    f32x4 acc0 = {0.f,0.f,0.f,0.f}, acc1 = {0.f,0.f,0.f,0.f};
    f32x4 acc2 = {0.f,0.f,0.f,0.f}, acc3 = {0.f,0.f,0.f,0.f};

    // B fragment base for this wave: fragment id f = (j*2+kh)*6 + nt6
    const unsigned short* __restrict__ bb =
        Bpk + (((size_t)(kq * 8 * 2) * 6 + nt6) << 10) + lane * 8;
    // ushort strides: per kh = 6<<10, per j = 12<<10

    #define MT_STEP(ACC, mnum, J, BH0, BL0, BH1, BL1) { \
        const int r_ = ((mnum) * 16 + l15 + (J)) & 63; \
        const int base_ = r_ << 6; \
        const int rs_ = r_ & 7; \
        { const int aoff_ = base_ + (((u) ^ rs_) << 3); \
          short8v ah_ = *(const short8v*)&sHi[aoff_]; \
          short8v al_ = *(const short8v*)&sLo[aoff_]; \
          ACC = MFMA16(ah_, BH0, ACC); ACC = MFMA16(ah_, BL0, ACC); \
          ACC = MFMA16(al_, BH0, ACC); ACC = MFMA16(al_, BL0, ACC); } \
        { const int aoff_ = base_ + ((((4 + u)) ^ rs_) << 3); \
          short8v ah_ = *(const short8v*)&sHi[aoff_]; \
          short8v al_ = *(const short8v*)&sLo[aoff_]; \
          ACC = MFMA16(ah_, BH1, ACC); ACC = MFMA16(ah_, BL1, ACC); \
          ACC = MFMA16(al_, BH1, ACC); ACC = MFMA16(al_, BL1, ACC); } }

    #pragma unroll
    for (int jj = 0; jj < 8; ++jj) {
        const int j = kq * 8 + jj;
        const unsigned short* bj = bb + (size_t)jj * (12 << 10);
        short8v bh0 = *(const short8v*)(bj);
        short8v bl0 = *(const short8v*)(bj + 512);
        short8v bh1 = *(const short8v*)(bj + (6 << 10));
        short8v bl1 = *(const short8v*)(bj + (6 << 10) + 512);
        MT_STEP(acc0, 0, j, bh0, bl0, bh1, bl1);
        MT_STEP(acc1, 1, j, bh0, bl0, bh1, bl1);
        MT_STEP(acc2, 2, j, bh0, bl0, bh1, bl1);
        MT_STEP(acc3, 3, j, bh0, bl0, bh1, bl1);
    }
    #undef MT_STEP

    // ---- C/D -> corrPart[wv]: col = lane&15, row = m*16 + (lane>>4)*4 + reg ----
    {
        const int rr = u * 4;
        #pragma unroll
        for (int reg = 0; reg < 4; ++reg) {
            corrPart[wv][rr + reg][l15]      = acc0[reg];
            corrPart[wv][16 + rr + reg][l15] = acc1[reg];
            corrPart[wv][32 + rr + reg][l15] = acc2[reg];
            corrPart[wv][48 + rr + reg][l15] = acc3[reg];
        }
    }
    __syncthreads();

    // ---- reduce 4 wave-slices, write partial (coalesced dwords) ----
    float* dst = part + ((size_t)((bs * 6 + nt6) * 2 + kz) << 10);
    #pragma unroll
    for (int e = tid; e < 1024; e += 256) {
        const int row = e >> 4, col = e & 15;
        dst[e] = (corrPart[0][row][col] + corrPart[1][row][col])
               + (corrPart[2][row][col] + corrPart[3][row][col]);
    }
}

// ---------------- epilogue: sum khalves, argmax, norm, dot, distance --------
__global__ __launch_bounds__(256)
void pf_epi(const float* __restrict__ sat, const float* __restrict__ grd,
            const float* __restrict__ part, float* __restrict__ out)
{
    __shared__ float corrE[64][17];
    __shared__ float redW[4];
    __shared__ int   orienL[16];

    const int bs  = blockIdx.y;
    const int nt6 = blockIdx.x;
    const int bg0 = nt6 * 16;
    const int tid = threadIdx.x;
    const int wv  = tid >> 6, lane = tid & 63;

    // sum the two K-half partials
    const float* p0 = part + ((size_t)((bs * 6 + nt6) * 2) << 10);
    const float* p1 = p0 + 1024;
    #pragma unroll
    for (int e = tid; e < 1024; e += 256)
        corrE[e >> 4][e & 15] = p0[e] + p1[e];

    // norm partial: 4096 floats over 256 threads
    {
        float np = 0.f;
        const float4* sb = (const float4*)(sat + (size_t)bs * HWC);
        #pragma unroll
        for (int t = tid; t < 1024; t += 256) {
            float4 v = sb[t];
            np = fmaf(v.x, v.x, fmaf(v.y, v.y, fmaf(v.z, v.z, fmaf(v.w, v.w, np))));
        }
        #pragma unroll
        for (int off = 32; off; off >>= 1) np += __shfl_xor(np, off);
        if (lane == 0) redW[wv] = np;
    }
    __syncthreads();

    const float nrm = sqrtf((redW[0] + redW[1]) + (redW[2] + redW[3]) + 1e-8f);

    // argmax per bg (first-max tie-break): wave wv -> bgc = wv*4..+3
    #pragma unroll
    for (int t = 0; t < 4; ++t) {
        const int bgc = wv * 4 + t;
        float v = corrE[lane][bgc];
        int idx = lane;
        #pragma unroll
        for (int off = 32; off; off >>= 1) {
            float ov = __shfl_xor(v, off);
            int   oi = __shfl_xor(idx, off);
            if (ov > v || (ov == v && oi < idx)) { v = ov; idx = oi; }
        }
        if (lane == 0) {
            orienL[bgc] = idx;
            out[OUT_ORIEN + bs * BG + bg0 + bgc] = (float)idx;
        }
    }
    __syncthreads();

    // fp32 dot + distance: wave wv -> bgc = wv*4..+3, lane = j
    #pragma unroll
    for (int t = 0; t < 4; ++t) {
        const int bgc = wv * 4 + t;
        const int bg = bg0 + bgc;
        const int r = (lane + orienL[bgc]) & 63;
        float s = 0.f;
        #pragma unroll
        for (int h = 0; h < 4; ++h) {
            const float4* sp = (const float4*)&sat[(((size_t)bs * 4 + h) * 64 + r) * 16];
            const float4* gp = (const float4*)&grd[(((size_t)bg * 4 + h) * 64 + lane) * 16];
            #pragma unroll
            for (int c4 = 0; c4 < 4; ++c4) {
                float4 sv = sp[c4];
                float4 gv = gp[c4];
                s = fmaf(sv.x, gv.x, fmaf(sv.y, gv.y, fmaf(sv.z, gv.z, fmaf(sv.w, gv.w, s))));
            }
        }
        #pragma unroll
        for (int off = 32; off; off >>= 1) s += __shfl_xor(s, off);
        if (lane == 0)
            out[OUT_DIST + (size_t)bg * BS + bs] = 2.f - 2.f * (s / nrm);
    }
}

// ---------------- fallback (R3, verified): used only if ws too small ----------------
__device__ __forceinline__ int satIdxFB(int hw, int c4) {
    return hw * 16 + 4 * ((c4 + (hw >> 1)) & 3);
}
__device__ __forceinline__ float rot_add(int baddr, float p) {
    return __int_as_float(__builtin_amdgcn_ds_bpermute(baddr, __float_as_int(p)));
}
__device__ __forceinline__ float dot_rev(const float4 s0, const float4 s1,
                                         const float4 s2, const float4 s3,
                                         const float* __restrict__ g) {
    float p0 = fmaf(s0.x, g[15], fmaf(s0.y, g[14], fmaf(s0.z, g[13], s0.w * g[12])));
    float p1 = fmaf(s1.x, g[11], fmaf(s1.y, g[10], fmaf(s1.z, g[ 9], s1.w * g[ 8])));
    float p2 = fmaf(s2.x, g[ 7], fmaf(s2.y, g[ 6], fmaf(s2.z, g[ 5], s2.w * g[ 4])));
    float p3 = fmaf(s3.x, g[ 3], fmaf(s3.y, g[ 2], fmaf(s3.z, g[ 1], s3.w * g[ 0])));
    return (p0 + p1) + (p2 + p3);
}
#define NB 8
__global__ __launch_bounds__(256)
void pf_fused_fb(const float* __restrict__ sat, const float* __restrict__ grd,
                 float* __restrict__ out)
{
    __shared__ float satL[H * W * C];
    __shared__ float partL[NB * 4 * W];
    __shared__ float sumL[4];
    __shared__ float dotP[NB * 4];
    __shared__ int   orienL[NB];
    const int bs = blockIdx.y, bg0 = blockIdx.x * NB;
    const int tid = threadIdx.x, wv = tid >> 6, lane = tid & 63;
    const float4* sp = (const float4*)(sat + (((size_t)bs * H + wv) * W + lane) * C);
    const float4 s0 = sp[0], s1 = sp[1], s2 = sp[2], s3 = sp[3];
    { const int hw = wv * W + lane;
      *(float4*)&satL[satIdxFB(hw,0)] = s0; *(float4*)&satL[satIdxFB(hw,1)] = s1;
      *(float4*)&satL[satIdxFB(hw,2)] = s2; *(float4*)&satL[satIdxFB(hw,3)] = s3; }
    { float a = fmaf(s0.x,s0.x,fmaf(s0.y,s0.y,fmaf(s0.z,s0.z,s0.w*s0.w)));
      float b = fmaf(s1.x,s1.x,fmaf(s1.y,s1.y,fmaf(s1.z,s1.z,s1.w*s1.w)));
      float c = fmaf(s2.x,s2.x,fmaf(s2.y,s2.y,fmaf(s2.z,s2.z,s2.w*s2.w)));
      float d = fmaf(s3.x,s3.x,fmaf(s3.y,s3.y,fmaf(s3.z,s3.z,s3.w*s3.w)));
      float s = (a+b)+(c+d);
      #pragma unroll
      for (int off = 32; off; off >>= 1) s += __shfl_xor(s, off);
      if (lane == 0) sumL[wv] = s; }
    const float* gpB = grd + (size_t)(bg0 * H + wv) * W * C;
    #pragma unroll
    for (int bp = 0; bp < NB/2; ++bp) {
        const float* gA = gpB + (2*bp) * HWC;
        const float* gB2 = gpB + (2*bp+1) * HWC;
        float accA = 0.f, accB = 0.f;
        int baddr = lane << 2;
        #pragma unroll 2
        for (int j = 0; j < W; ++j) {
            float pA = dot_rev(s0,s1,s2,s3, gA + j*C);
            float pB = dot_rev(s0,s1,s2,s3, gB2 + j*C);
            accA += rot_add(baddr, pA); accB += rot_add(baddr, pB);
            baddr = (baddr + 4) & 255;
        }
        partL[((2*bp)*4 + wv)*W + lane] = accA;
        partL[((2*bp+1)*4 + wv)*W + lane] = accB;
    }
    __syncthreads();
    for (int b = wv; b < NB; b += 4) {
        float v = (partL[(b*4+0)*W+lane] + partL[(b*4+1)*W+lane])
                + (partL[(b*4+2)*W+lane] + partL[(b*4+3)*W+lane]);
        int idx = lane;
        #pragma unroll
        for (int off = 32; off; off >>= 1) {
            float ov = __shfl_xor(v, off); int oi = __shfl_xor(idx, off);
            if (ov > v || (ov == v && oi < idx)) { v = ov; idx = oi; }
        }
        if (lane == 0) { orienL[b] = idx; out[OUT_ORIEN + bs*BG + (bg0+b)] = (float)idx; }
    }
    __syncthreads();
    const float nrm = sqrtf(sumL[0]+sumL[1]+sumL[2]+sumL[3] + 1e-8f);
    { float dp[NB];
      #pragma unroll
      for (int b = 0; b < NB; ++b) {
          const int row = (lane + orienL[b]) & 63;
          const float* gRow = grd + (((size_t)(bg0+b)*H + wv)*W + lane)*C;
          float s = 0.f;
          #pragma unroll
          for (int c4 = 0; c4 < 4; ++c4) {
              float4 sv = *(const float4*)&satL[satIdxFB(wv*W+row, c4)];
              float4 gv = *(const float4*)(gRow + 4*c4);
              s = fmaf(sv.x,gv.x, fmaf(sv.y,gv.y, fmaf(sv.z,gv.z, fmaf(sv.w,gv.w, s))));
          }
          dp[b] = s;
      }
      #pragma unroll
      for (int b = 0; b < NB; ++b) {
          float s = dp[b];
          #pragma unroll
          for (int off = 32; off; off >>= 1) s += __shfl_xor(s, off);
          if (lane == 0) dotP[b*4 + wv] = s;
      } }
    __syncthreads();
    if (tid < NB) {
        float d = ((dotP[tid*4+0]+dotP[tid*4+1])+(dotP[tid*4+2]+dotP[tid*4+3])) / nrm;
        out[OUT_DIST + (size_t)(bg0+tid)*BS + bs] = 2.f - 2.f*d;
    }
}

extern "C" void kernel_launch(void* const* d_in, const int* in_sizes, int n_in,
                              void* d_out, int out_size, void* d_ws, size_t ws_size,
                              hipStream_t stream) {
    const float* sat = (const float*)d_in[0];
    const float* grd = (const float*)d_in[1];
    float* out = (float*)d_out;

    if (ws_size < WS_NEEDED) {
        hipMemcpyAsync(out,             sat, (size_t)SAT_ELEMS * sizeof(float),
                       hipMemcpyDeviceToDevice, stream);
        hipMemcpyAsync(out + SAT_ELEMS, grd, (size_t)SAT_ELEMS * sizeof(float),
                       hipMemcpyDeviceToDevice, stream);
        dim3 grid(BG / NB, BS);
        pf_fused_fb<<<grid, 256, 0, stream>>>(sat, grd, out);
        return;
    }

    unsigned short* Bpk = (unsigned short*)d_ws;
    float* part = (float*)((char*)d_ws + WS_PART_OFF);

    pf_pack_b<<<96, 512, 0, stream>>>(sat, grd, Bpk, out);
    pf_corr<<<dim3(6, BS, 2), 256, 0, stream>>>(sat, Bpk, part);
    pf_epi<<<dim3(6, BS), 256, 0, stream>>>(sat, grd, part, out);
}